// Round 13
// baseline (87.911 us; speedup 1.0000x reference)
//
#include <hip/hip_runtime.h>
#include <cstdint>

#define D_MODEL   768
#define D_STATE   64
#define D_INNER   1536
#define NHEADS    24
#define HEADDIM   64
#define D_PROJ    3248
#define BATCH     2
#define SEQ       1024
#define ROWS      (BATCH*SEQ)   // 2048
#define LN_EPS    1e-5f
#define A_FLOOR   1e-4f
#define QC        64            // chunk length
#define NCH       (SEQ/QC)      // 16
#define LSTR      72            // LDS row stride in shorts (144B = 9*16B)
#define COL_DT    3200          // 2*D_INNER + 2*D_STATE
#define COL_DA    3224          // COL_DT + NHEADS

// packed-operand geometry: [kt][rg][c4][64 rows][8 bf16] (4KB per (kt,rg))
#define RG_U    32
#define RG_WIN  52
#define RG_WO   12
#define KT_1    24
#define KT_2    48

typedef __attribute__((ext_vector_type(8))) short short8;
typedef __attribute__((ext_vector_type(4))) float f32x4;

__device__ __forceinline__ unsigned short f2bf(float f) {
  union { float f; uint32_t u; } v; v.f = f;
  uint32_t r = (v.u + 0x7FFFu + ((v.u >> 16) & 1u)) >> 16;
  return (unsigned short)r;
}
__device__ __forceinline__ float bf2f(unsigned short u) {
  union { uint32_t u; float f; } v; v.u = (uint32_t)u << 16;
  return v.f;
}
__device__ __forceinline__ void storeC(float v, float* p) { *p = v; }
__device__ __forceinline__ void storeC(float v, unsigned short* p) { *p = f2bf(v); }

__device__ __forceinline__ void gload_lds16(const void* g, void* l) {
  __builtin_amdgcn_global_load_lds(
      (const __attribute__((address_space(1))) unsigned int*)g,
      (__attribute__((address_space(3))) unsigned int*)l, 16, 0, 0);
}

template <int N>
__device__ __forceinline__ void wait_vm() {
  static_assert(N == 0 || N == 2 || N == 3 || N == 4 || N == 6 || N == 8,
                "unsupported vmcnt");
  if constexpr (N == 0) asm volatile("s_waitcnt vmcnt(0)" ::: "memory");
  else if constexpr (N == 2) asm volatile("s_waitcnt vmcnt(2)" ::: "memory");
  else if constexpr (N == 3) asm volatile("s_waitcnt vmcnt(3)" ::: "memory");
  else if constexpr (N == 4) asm volatile("s_waitcnt vmcnt(4)" ::: "memory");
  else if constexpr (N == 6) asm volatile("s_waitcnt vmcnt(6)" ::: "memory");
  else if constexpr (N == 8) asm volatile("s_waitcnt vmcnt(8)" ::: "memory");
}

__device__ __forceinline__ float softplusf(float x) {
  return (x > 20.f) ? x : log1pf(expf(x));
}
__device__ __forceinline__ float wave_prefix_incl(float v, int lane) {
#pragma unroll
  for (int o = 1; o < 64; o <<= 1) {
    float w = __shfl_up(v, o);
    if (lane >= o) v += w;
  }
  return v;
}

// ---------------------------------------------------------------------------
// Pack f32 row-major -> bf16 [kt][rg][c][64][8].
// ---------------------------------------------------------------------------
__global__ __launch_bounds__(256) void pack_all_kernel(
    const float* __restrict__ u, const float* __restrict__ Win,
    const float* __restrict__ Wout, unsigned short* __restrict__ upk,
    unsigned short* __restrict__ Winpk, unsigned short* __restrict__ Wopk) {
  int b = blockIdx.x;
  const float* src; unsigned short* dst; int K, RG, kt, rg, srcRows;
  if (b < KT_1 * RG_U) {
    src = u; dst = upk; K = 768; RG = RG_U; kt = b / RG_U; rg = b % RG_U; srcRows = ROWS;
  } else if (b < KT_1 * RG_U + KT_1 * RG_WIN) {
    int i = b - KT_1 * RG_U;
    src = Win; dst = Winpk; K = 768; RG = RG_WIN; kt = i / RG_WIN; rg = i % RG_WIN; srcRows = D_PROJ;
  } else {
    int i = b - KT_1 * RG_U - KT_1 * RG_WIN;
    src = Wout; dst = Wopk; K = 1536; RG = RG_WO; kt = i / RG_WO; rg = i % RG_WO; srcRows = D_MODEL;
  }
  const int t = threadIdx.x;
  const int lr = t >> 2, cq = t & 3;
  const int R = rg * 64 + lr;
  float4 v0 = make_float4(0.f, 0.f, 0.f, 0.f), v1 = v0;
  if (R < srcRows) {
    const float* p = src + (size_t)R * K + kt * 32 + cq * 8;
    v0 = *(const float4*)p;
    v1 = *(const float4*)(p + 4);
  }
  ushort4 oa, ob;
  oa.x = f2bf(v0.x); oa.y = f2bf(v0.y); oa.z = f2bf(v0.z); oa.w = f2bf(v0.w);
  ob.x = f2bf(v1.x); ob.y = f2bf(v1.y); ob.z = f2bf(v1.z); ob.w = f2bf(v1.w);
  unsigned short* o = dst + ((size_t)(kt * RG + rg) * 4 + cq) * 512 + lr * 8;
  *(ushort4*)o = oa;
  *(ushort4*)(o + 4) = ob;
}

// ---------------------------------------------------------------------------
// MFMA bf16 GEMM (NT), packed operands. 3-buffer / prefetch-2 / 1 barrier per
// K-iter, XCD panel swizzle, optional in-block split-K (SPLIT=2).
// EPILN: blocks covering cols [3072,3200) also LayerNorm their B/C slices
// straight from the f32 accumulators (waves 0,1 = B-half, waves 2,3 = C-half;
// per row: 4-reg sum + shfl_xor 1..8 within the 16-lane column group).
// ---------------------------------------------------------------------------
template <int TBM, int TBN, int GX, int GY, bool XMAJOR, int SPLIT, bool EPILN,
          typename CT>
__global__ __launch_bounds__(256 * SPLIT) void gemm_bt_bf16(
    const unsigned short* __restrict__ A, const unsigned short* __restrict__ B,
    CT* __restrict__ C, int aRG, int bRG, int M, int N, int K,
    const float* __restrict__ LNg0, const float* __restrict__ LNb0,
    const float* __restrict__ LNg1, const float* __restrict__ LNb1,
    unsigned short* __restrict__ BCout) {
  constexpr int MF = TBM / 32;
  constexpr int NF = TBN / 32;
  constexpr int NSA = TBM / 16;
  constexpr int NSB = TBN / 16;
  constexpr int LPW = (NSA + NSB) / 4;
  static_assert((NSA + NSB) % 4 == 0, "segments must split evenly over waves");
  constexpr int NWG = GX * GY;
  constexpr int PER = NWG / 8;
  static_assert(NWG % 8 == 0, "grid must split evenly over 8 XCDs");
  __shared__ unsigned short Asm[SPLIT][3][TBM * 32];
  __shared__ unsigned short Bsm[SPLIT][3][TBN * 32];

  const int tid = threadIdx.x;
  const int w = tid >> 6, lane = tid & 63;
  const int khalf = w >> 2;        // 0 for SPLIT=1
  const int wv = w & 3;
  const int kTiles = (K / SPLIT) >> 5;
  const int ktBase = khalf * kTiles;

  const int g = (blockIdx.x & 7) * PER + (blockIdx.x >> 3);
  int bx, by;
  if constexpr (XMAJOR) { by = g / GX; bx = g - by * GX; }
  else                  { bx = g / GY; by = g - bx * GY; }
  const int bm = by * TBM, bn = bx * TBN;

  const int wm = (wv & 1) * (TBM / 2);
  const int wn = (wv >> 1) * (TBN / 2);
  const int gq = lane >> 4, r = lane & 15;

  f32x4 acc[MF][NF];
#pragma unroll
  for (int i = 0; i < MF; ++i)
#pragma unroll
    for (int j = 0; j < NF; ++j) acc[i][j] = (f32x4){0.f, 0.f, 0.f, 0.f};

  auto stage = [&](int t, int buf) {
    const int kt = ktBase + t;
    for (int s = wv; s < NSA + NSB; s += 4) {
      if (s < NSA) {
        const unsigned short* src =
            A + ((size_t)kt * aRG + (bm >> 6) + (s >> 2)) * 2048 + (s & 3) * 512 + lane * 8;
        gload_lds16(src, (void*)(&Asm[khalf][buf][s * 512]));
      } else {
        int s2 = s - NSA;
        const unsigned short* src =
            B + ((size_t)kt * bRG + (bn >> 6) + (s2 >> 2)) * 2048 + (s2 & 3) * 512 + lane * 8;
        gload_lds16(src, (void*)(&Bsm[khalf][buf][s2 * 512]));
      }
    }
  };

  stage(0, 0);
  stage(1, 1);

  int cur = 0;
  for (int t = 0; t < kTiles; ++t) {
    if (t + 1 < kTiles) wait_vm<LPW>();
    else                wait_vm<0>();
    __builtin_amdgcn_s_barrier();
    asm volatile("" ::: "memory");

    if (t + 2 < kTiles) stage(t + 2, (t + 2) % 3);

    short8 a[MF], b[NF];
#pragma unroll
    for (int mf = 0; mf < MF; ++mf) {
      int ra = wm + mf * 16 + r;
      a[mf] = *(const short8*)&Asm[khalf][cur][(ra >> 6) * 2048 + gq * 512 + (ra & 63) * 8];
    }
#pragma unroll
    for (int nf = 0; nf < NF; ++nf) {
      int rb = wn + nf * 16 + r;
      b[nf] = *(const short8*)&Bsm[khalf][cur][(rb >> 6) * 2048 + gq * 512 + (rb & 63) * 8];
    }
#pragma unroll
    for (int mf = 0; mf < MF; ++mf)
#pragma unroll
      for (int nf = 0; nf < NF; ++nf)
        acc[mf][nf] = __builtin_amdgcn_mfma_f32_16x16x32_bf16(a[mf], b[nf], acc[mf][nf], 0, 0, 0);

    cur = (cur + 1) % 3;
  }

  if constexpr (SPLIT == 2) {
    __syncthreads();
    float* red = (float*)&Asm[0][0][0];
    if (khalf == 1) {
#pragma unroll
      for (int mf = 0; mf < MF; ++mf)
#pragma unroll
        for (int nf = 0; nf < NF; ++nf)
#pragma unroll
          for (int q = 0; q < 4; ++q)
            red[(size_t)wv * 1024 + ((mf * NF + nf) * 4 + q) * 64 + lane] = acc[mf][nf][q];
    }
    __syncthreads();
    if (khalf == 1) return;
#pragma unroll
    for (int mf = 0; mf < MF; ++mf)
#pragma unroll
      for (int nf = 0; nf < NF; ++nf)
#pragma unroll
        for (int q = 0; q < 4; ++q)
          acc[mf][nf][q] += red[(size_t)wv * 1024 + ((mf * NF + nf) * 4 + q) * 64 + lane];
  }

  // C write: D row = (lane>>4)*4 + q, col = lane&15 (m89-verified layout)
#pragma unroll
  for (int mf = 0; mf < MF; ++mf) {
#pragma unroll
    for (int nf = 0; nf < NF; ++nf) {
      int col = bn + wn + nf * 16 + r;
      if (col < N) {
#pragma unroll
        for (int q = 0; q < 4; ++q) {
          int row = bm + wm + mf * 16 + gq * 4 + q;
          storeC(acc[mf][nf][q], &C[(size_t)row * N + col]);
        }
      }
    }
  }

  // fused LayerNorm epilogue (GEMM1 only, tile column covering cols 3072-3199)
  if constexpr (EPILN) {
    if (bn == 2 * D_INNER) {
      const float* gma = (wn == 0) ? LNg0 : LNg1;
      const float* bta = (wn == 0) ? LNb0 : LNb1;
      const int half = (wn == 0) ? 0 : 64;
#pragma unroll
      for (int mf = 0; mf < MF; ++mf) {
#pragma unroll
        for (int q = 0; q < 4; ++q) {
          float s1 = 0.f, s2 = 0.f;
#pragma unroll
          for (int nf = 0; nf < NF; ++nf) {
            float v = acc[mf][nf][q];
            s1 += v; s2 += v * v;
          }
#pragma unroll
          for (int o = 1; o < 16; o <<= 1) {
            s1 += __shfl_xor(s1, o);
            s2 += __shfl_xor(s2, o);
          }
          float mean = s1 * (1.f / 64.f);
          float var = s2 * (1.f / 64.f) - mean * mean;
          float rs = rsqrtf(fmaxf(var, 0.f) + LN_EPS);
          int row = bm + wm + mf * 16 + gq * 4 + q;
#pragma unroll
          for (int nf = 0; nf < NF; ++nf) {
            int n = nf * 16 + r;
            BCout[(size_t)row * 128 + half + n] =
                f2bf((acc[mf][nf][q] - mean) * rs * gma[n] + bta[n]);
          }
        }
      }
    }
  }
}

// ---------------------------------------------------------------------------
// Fused chunk_state + interchunk: grid = bh(48) x p-quarter(4). Per block:
// loop 16 chunks; T[n][p0:p0+16] = sum_s (B[s][n]*coeff_s) * X[s][p];
// scan S = E_c*S + T in accumulator registers; S_in stored per chunk.
// B/X register-prefetched one chunk ahead (loads hide under MFMA phase).
// ---------------------------------------------------------------------------
__global__ __launch_bounds__(256) void scan_fused_kernel(
    const unsigned short* __restrict__ proj, const unsigned short* __restrict__ BC,
    const float* __restrict__ dt_bias, float* __restrict__ Sinbuf) {
  const int part = blockIdx.x & 3, bh = blockIdx.x >> 2;
  const int b = bh / NHEADS, hh = bh % NHEADS;
  const int p0 = part * 16;
  const int tid = threadIdx.x;
  const int w = tid >> 6, l = tid & 63, r16 = l & 15, g = l >> 4;

  __shared__ unsigned short BT[64 * LSTR];   // [n][s], coeff folded in
  __shared__ unsigned short XT[16 * LSTR];   // [p-local][s], raw bits
  __shared__ float coeffA[NCH][QC];
  __shared__ float etotA[NCH];

  // upfront: all 16 chunks' coeff/etot (wave w handles chunks w, w+4, w+8, w+12)
  {
    const float dtb = dt_bias[hh];
#pragma unroll
    for (int j = 0; j < 4; ++j) {
      int c = w + j * 4;
      int rr = b * SEQ + c * QC + l;
      float ddt = bf2f(proj[(size_t)rr * D_PROJ + COL_DT + hh]);
      float dA  = bf2f(proj[(size_t)rr * D_PROJ + COL_DA + hh]);
      float DT = softplusf(ddt + dtb);
      float Aa = fminf(-softplusf(dA), -A_FLOOR);
      float cs = wave_prefix_incl(Aa * DT, l);
      float tot = __shfl(cs, 63);
      coeffA[c][l] = DT * __expf(tot - cs);
      if (l == 63) etotA[c] = __expf(tot);
    }
  }
  __syncthreads();

  ushort4 rB[4];
  ushort4 rX;
  auto loadRegs = [&](int c) {
#pragma unroll
    for (int j = 0; j < 4; ++j) {
      int i = tid + j * 256;
      int s = i >> 4, q = (i & 15) * 4;
      rB[j] = *(const ushort4*)(BC + (size_t)(b * SEQ + c * QC + s) * 128 + q);
    }
    int s = tid >> 2, pq = (tid & 3) * 4;
    rX = *(const ushort4*)(proj + (size_t)(b * SEQ + c * QC + s) * D_PROJ +
                           D_INNER + hh * 64 + p0 + pq);
  };

  loadRegs(0);
  f32x4 S = (f32x4){0.f, 0.f, 0.f, 0.f};

  for (int c = 0; c < NCH; ++c) {
    // stage from regs (transpose-on-write); coeff folded into B side
#pragma unroll
    for (int j = 0; j < 4; ++j) {
      int i = tid + j * 256;
      int s = i >> 4, q = (i & 15) * 4;
      float cf = coeffA[c][s];
      BT[(q + 0) * LSTR + s] = f2bf(bf2f(rB[j].x) * cf);
      BT[(q + 1) * LSTR + s] = f2bf(bf2f(rB[j].y) * cf);
      BT[(q + 2) * LSTR + s] = f2bf(bf2f(rB[j].z) * cf);
      BT[(q + 3) * LSTR + s] = f2bf(bf2f(rB[j].w) * cf);
    }
    {
      int s = tid >> 2, pq = (tid & 3) * 4;
      XT[(pq + 0) * LSTR + s] = rX.x;
      XT[(pq + 1) * LSTR + s] = rX.y;
      XT[(pq + 2) * LSTR + s] = rX.z;
      XT[(pq + 3) * LSTR + s] = rX.w;
    }
    __syncthreads();

    if (c + 1 < NCH) loadRegs(c + 1);   // prefetch next chunk (regs dead now)

    f32x4 T = (f32x4){0.f, 0.f, 0.f, 0.f};
#pragma unroll
    for (int kk = 0; kk < 2; ++kk) {
      short8 a = *(const short8*)&BT[(w * 16 + r16) * LSTR + kk * 32 + g * 8];
      short8 bf = *(const short8*)&XT[r16 * LSTR + kk * 32 + g * 8];
      T = __builtin_amdgcn_mfma_f32_16x16x32_bf16(a, bf, T, 0, 0, 0);
    }

    const float E = etotA[c];
    size_t base = (size_t)(bh * NCH + c) * 4096;
#pragma unroll
    for (int q = 0; q < 4; ++q) {
      int n = w * 16 + g * 4 + q;
      Sinbuf[base + (size_t)n * 64 + p0 + r16] = S[q];   // state BEFORE chunk c
      S[q] = fmaf(E, S[q], T[q]);
    }
    __syncthreads();   // BT/XT reuse protection
  }
}

// ---------------------------------------------------------------------------
// chunk_output (MFMA): G=Cc@Bc^T, CS=Cc@SinT, mask G->W, Y=exp*CS+W@X+D*x,
// silu(z) gate -> PACKED bf16 Ypk. csum/DT computed locally from proj.
// ---------------------------------------------------------------------------
__global__ __launch_bounds__(256) void chunk_output_kernel(
    const unsigned short* __restrict__ proj, const unsigned short* __restrict__ BC,
    const float* __restrict__ dt_bias, const float* __restrict__ Sinbuf,
    const float* __restrict__ Dv, unsigned short* __restrict__ Ybf) {
  const int blk = blockIdx.x;
  const int c = blk & (NCH - 1), bh = blk >> 4;
  const int b = bh / NHEADS, hh = bh % NHEADS;
  const int tid = threadIdx.x;

  __shared__ unsigned short Cc[64 * LSTR];    // [t][n]
  __shared__ unsigned short Bc[64 * LSTR];    // [s][n]
  __shared__ unsigned short SinT[64 * LSTR];  // [p][n]
  __shared__ unsigned short XT[64 * LSTR];    // [p][s]
  __shared__ unsigned short Wl[64 * LSTR];    // [t][s]
  __shared__ float csum[QC];
  __shared__ float DTs[QC];

  if (tid < 64) {
    int rr = b * SEQ + c * QC + tid;
    float ddt = bf2f(proj[(size_t)rr * D_PROJ + COL_DT + hh]);
    float dA  = bf2f(proj[(size_t)rr * D_PROJ + COL_DA + hh]);
    float DT = softplusf(ddt + dt_bias[hh]);
    float Aa = fminf(-softplusf(dA), -A_FLOOR);
    csum[tid] = wave_prefix_incl(Aa * DT, tid);
    DTs[tid] = DT;
  }

  const size_t sin_base = (size_t)blk * 4096;
  for (int i = tid; i < 1024; i += 256) {
    int s = i >> 4;
    int q = (i & 15) * 4;
    int r = b * SEQ + c * QC + s;
    ushort4 bv = *(const ushort4*)(BC + (size_t)r * 128 + q);
    ushort4 cv = *(const ushort4*)(BC + (size_t)r * 128 + 64 + q);
    ushort4 xv = *(const ushort4*)(proj + (size_t)r * D_PROJ + D_INNER + hh * 64 + q);
    float4 sv = *(const float4*)(Sinbuf + sin_base + (size_t)s * 64 + q);
    *(ushort4*)&Cc[s * LSTR + q] = cv;
    *(ushort4*)&Bc[s * LSTR + q] = bv;
    XT[(q + 0) * LSTR + s] = xv.x;
    XT[(q + 1) * LSTR + s] = xv.y;
    XT[(q + 2) * LSTR + s] = xv.z;
    XT[(q + 3) * LSTR + s] = xv.w;
    SinT[(q + 0) * LSTR + s] = f2bf(sv.x);
    SinT[(q + 1) * LSTR + s] = f2bf(sv.y);
    SinT[(q + 2) * LSTR + s] = f2bf(sv.z);
    SinT[(q + 3) * LSTR + s] = f2bf(sv.w);
  }
  __syncthreads();

  const int w = tid >> 6, l = tid & 63;
  const int r16 = l & 15, g = l >> 4;

  f32x4 accg[4], accy[4];
#pragma unroll
  for (int i = 0; i < 4; ++i) {
    accg[i] = (f32x4){0.f, 0.f, 0.f, 0.f};
    accy[i] = (f32x4){0.f, 0.f, 0.f, 0.f};
  }

#pragma unroll
  for (int kk = 0; kk < 2; ++kk) {
    short8 a = *(const short8*)&Cc[(w * 16 + r16) * LSTR + kk * 32 + g * 8];
#pragma unroll
    for (int f = 0; f < 4; ++f) {
      short8 bf = *(const short8*)&Bc[(f * 16 + r16) * LSTR + kk * 32 + g * 8];
      accg[f] = __builtin_amdgcn_mfma_f32_16x16x32_bf16(a, bf, accg[f], 0, 0, 0);
    }
#pragma unroll
    for (int f = 0; f < 4; ++f) {
      short8 bf = *(const short8*)&SinT[(f * 16 + r16) * LSTR + kk * 32 + g * 8];
      accy[f] = __builtin_amdgcn_mfma_f32_16x16x32_bf16(a, bf, accy[f], 0, 0, 0);
    }
  }

  float cst[4], dsc[4];
#pragma unroll
  for (int q = 0; q < 4; ++q) {
    cst[q] = csum[w * 16 + g * 4 + q];
    dsc[q] = __expf(cst[q]);
  }
#pragma unroll
  for (int sf = 0; sf < 4; ++sf) {
    int s = sf * 16 + r16;
    float cs_s = csum[s], dt_s = DTs[s];
#pragma unroll
    for (int q = 0; q < 4; ++q) {
      int t = w * 16 + g * 4 + q;
      float wv = (s <= t) ? accg[sf][q] * __expf(cst[q] - cs_s) * dt_s : 0.f;
      Wl[t * LSTR + s] = f2bf(wv);
    }
  }
#pragma unroll
  for (int f = 0; f < 4; ++f)
#pragma unroll
    for (int q = 0; q < 4; ++q) accy[f][q] *= dsc[q];
  __syncthreads();

#pragma unroll
  for (int kk = 0; kk < 2; ++kk) {
    short8 a = *(const short8*)&Wl[(w * 16 + r16) * LSTR + kk * 32 + g * 8];
#pragma unroll
    for (int f = 0; f < 4; ++f) {
      short8 bf = *(const short8*)&XT[(f * 16 + r16) * LSTR + kk * 32 + g * 8];
      accy[f] = __builtin_amdgcn_mfma_f32_16x16x32_bf16(a, bf, accy[f], 0, 0, 0);
    }
  }

  const float Dh = Dv[hh];
  const int rg = b * 16 + c;
#pragma unroll
  for (int pf = 0; pf < 4; ++pf) {
    int p = pf * 16 + r16;
    int col = hh * 64 + p;
    int kt = col >> 5;
    int cseg = (col >> 3) & 3;
    int jj = p & 7;
    size_t base = ((size_t)(kt * RG_U + rg) * 4 + cseg) * 512 + jj;
#pragma unroll
    for (int q = 0; q < 4; ++q) {
      int t = w * 16 + g * 4 + q;
      int rr = b * SEQ + c * QC + t;
      float x = bf2f(proj[(size_t)rr * D_PROJ + D_INNER + hh * 64 + p]);
      float z = bf2f(proj[(size_t)rr * D_PROJ + hh * 64 + p]);
      float y = accy[pf][q] + Dh * x;
      Ybf[base + (size_t)t * 8] = f2bf(y * (z / (1.f + __expf(-z))));
    }
  }
}

// ---------------------------------------------------------------------------
// Launch: 5 dispatches (was 7)
// ---------------------------------------------------------------------------
extern "C" void kernel_launch(void* const* d_in, const int* in_sizes, int n_in,
                              void* d_out, int out_size, void* d_ws, size_t ws_size,
                              hipStream_t stream) {
  const float* u       = (const float*)d_in[0];
  const float* Win     = (const float*)d_in[1];
  const float* Wout    = (const float*)d_in[2];
  const float* dt_bias = (const float*)d_in[3];
  const float* Dv      = (const float*)d_in[4];
  const float* Bg      = (const float*)d_in[5];
  const float* Bb      = (const float*)d_in[6];
  const float* Cg      = (const float*)d_in[7];
  const float* Cb      = (const float*)d_in[8];
  float* out = (float*)d_out;

  float* ws = (float*)d_ws;
  unsigned short* projsh = (unsigned short*)ws;                       // 6.65M sh
  float* after_proj = ws + (size_t)ROWS * D_PROJ / 2;
  unsigned short* BCsh = (unsigned short*)after_proj;                 // 262K sh
  float* regionA = after_proj + (size_t)ROWS * 128 / 2;               // Winpk/Ypk
  float* Sinbuf  = regionA + 1600000;                                 // 768*4096 f32
  float* WopkF   = Sinbuf + (size_t)BATCH * NHEADS * NCH * 4096;

  // aliases (lifetimes verified):
  unsigned short* upk   = (unsigned short*)Sinbuf;   // dead after GEMM1; scan writes Sinbuf later
  unsigned short* Winpk = (unsigned short*)regionA;  // dead after GEMM1
  unsigned short* Ypk   = (unsigned short*)regionA;  // written by chunk_output
  unsigned short* Wopk  = (unsigned short*)WopkF;    // standalone

  // 1) cast+pack
  pack_all_kernel<<<KT_1 * RG_U + KT_1 * RG_WIN + KT_2 * RG_WO, 256, 0, stream>>>(
      u, Win, Wout, upk, Winpk, Wopk);

  // 2) proj = u @ Win.T -> bf16, fused LN(B),LN(C) -> BCsh
  gemm_bt_bf16<128, 128, 26, 16, false, 1, true, unsigned short>
      <<<416, 256, 0, stream>>>(upk, Winpk, projsh, RG_U, RG_WIN,
                                ROWS, D_PROJ, D_MODEL, Bg, Bb, Cg, Cb, BCsh);

  // 3) fused chunk_state + interchunk -> Sinbuf
  scan_fused_kernel<<<BATCH * NHEADS * 4, 256, 0, stream>>>(
      projsh, BCsh, dt_bias, Sinbuf);

  // 4) chunk_output -> packed Ypk
  chunk_output_kernel<<<BATCH * NHEADS * NCH, 256, 0, stream>>>(
      projsh, BCsh, dt_bias, Sinbuf, Dv, Ypk);

  // 5) out = Y @ Wout.T (in-block split-K=2, direct write)
  gemm_bt_bf16<64, 64, 12, 32, true, 2, false, float>
      <<<384, 512, 0, stream>>>(Ypk, Wopk, out, RG_U, RG_WO,
                                ROWS, D_MODEL, D_INNER,
                                nullptr, nullptr, nullptr, nullptr, nullptr);
}

// Round 14
// 78.281 us; speedup vs baseline: 1.1230x; 1.1230x over previous
//
#include <hip/hip_runtime.h>
#include <cstdint>

#define D_MODEL   768
#define D_STATE   64
#define D_INNER   1536
#define NHEADS    24
#define HEADDIM   64
#define D_PROJ    3248
#define BATCH     2
#define SEQ       1024
#define ROWS      (BATCH*SEQ)   // 2048
#define LN_EPS    1e-5f
#define A_FLOOR   1e-4f
#define QC        64            // chunk length
#define NCH       (SEQ/QC)      // 16
#define LSTR      72            // LDS row stride in shorts (144B = 9*16B)

// packed-operand geometry: [kt][rg][c4][64 rows][8 bf16] (4KB per (kt,rg))
#define RG_U    32
#define RG_WIN  52
#define RG_WO   12
#define KT_1    24
#define KT_2    48

typedef __attribute__((ext_vector_type(8))) short short8;
typedef __attribute__((ext_vector_type(4))) float f32x4;

__device__ __forceinline__ unsigned short f2bf(float f) {
  union { float f; uint32_t u; } v; v.f = f;
  uint32_t r = (v.u + 0x7FFFu + ((v.u >> 16) & 1u)) >> 16;
  return (unsigned short)r;
}
__device__ __forceinline__ float bf2f(unsigned short u) {
  union { uint32_t u; float f; } v; v.u = (uint32_t)u << 16;
  return v.f;
}
__device__ __forceinline__ void storeC(float v, float* p) { *p = v; }
__device__ __forceinline__ void storeC(float v, unsigned short* p) { *p = f2bf(v); }

__device__ __forceinline__ void gload_lds16(const void* g, void* l) {
  __builtin_amdgcn_global_load_lds(
      (const __attribute__((address_space(1))) unsigned int*)g,
      (__attribute__((address_space(3))) unsigned int*)l, 16, 0, 0);
}

template <int N>
__device__ __forceinline__ void wait_vm() {
  static_assert(N == 0 || N == 2 || N == 3 || N == 4 || N == 6 || N == 8,
                "unsupported vmcnt");
  if constexpr (N == 0) asm volatile("s_waitcnt vmcnt(0)" ::: "memory");
  else if constexpr (N == 2) asm volatile("s_waitcnt vmcnt(2)" ::: "memory");
  else if constexpr (N == 3) asm volatile("s_waitcnt vmcnt(3)" ::: "memory");
  else if constexpr (N == 4) asm volatile("s_waitcnt vmcnt(4)" ::: "memory");
  else if constexpr (N == 6) asm volatile("s_waitcnt vmcnt(6)" ::: "memory");
  else if constexpr (N == 8) asm volatile("s_waitcnt vmcnt(8)" ::: "memory");
}

// ---------------------------------------------------------------------------
// Pack f32 row-major -> bf16 [kt][rg][c][64][8].
// ---------------------------------------------------------------------------
__global__ __launch_bounds__(256) void pack_all_kernel(
    const float* __restrict__ u, const float* __restrict__ Win,
    const float* __restrict__ Wout, unsigned short* __restrict__ upk,
    unsigned short* __restrict__ Winpk, unsigned short* __restrict__ Wopk) {
  int b = blockIdx.x;
  const float* src; unsigned short* dst; int K, RG, kt, rg, srcRows;
  if (b < KT_1 * RG_U) {
    src = u; dst = upk; K = 768; RG = RG_U; kt = b / RG_U; rg = b % RG_U; srcRows = ROWS;
  } else if (b < KT_1 * RG_U + KT_1 * RG_WIN) {
    int i = b - KT_1 * RG_U;
    src = Win; dst = Winpk; K = 768; RG = RG_WIN; kt = i / RG_WIN; rg = i % RG_WIN; srcRows = D_PROJ;
  } else {
    int i = b - KT_1 * RG_U - KT_1 * RG_WIN;
    src = Wout; dst = Wopk; K = 1536; RG = RG_WO; kt = i / RG_WO; rg = i % RG_WO; srcRows = D_MODEL;
  }
  const int t = threadIdx.x;
  const int lr = t >> 2, cq = t & 3;
  const int R = rg * 64 + lr;
  float4 v0 = make_float4(0.f, 0.f, 0.f, 0.f), v1 = v0;
  if (R < srcRows) {
    const float* p = src + (size_t)R * K + kt * 32 + cq * 8;
    v0 = *(const float4*)p;
    v1 = *(const float4*)(p + 4);
  }
  ushort4 oa, ob;
  oa.x = f2bf(v0.x); oa.y = f2bf(v0.y); oa.z = f2bf(v0.z); oa.w = f2bf(v0.w);
  ob.x = f2bf(v1.x); ob.y = f2bf(v1.y); ob.z = f2bf(v1.z); ob.w = f2bf(v1.w);
  unsigned short* o = dst + ((size_t)(kt * RG + rg) * 4 + cq) * 512 + lr * 8;
  *(ushort4*)o = oa;
  *(ushort4*)(o + 4) = ob;
}

// ---------------------------------------------------------------------------
// MFMA bf16 GEMM (NT), packed operands. 3-buffer / prefetch-distance-2 /
// ONE barrier per K-iter. XCD panel swizzle. SPLIT=2: in-block split-K with
// 2*256 threads (waves 0-3 = K-half 0, waves 4-7 = K-half 1 on private LDS
// pipelines), f32 partial merge via LDS in epilogue.
// WAR safety: stage(t+2) targets buf[(t+2)%3] = buf[(t-1)%3]; all waves
// finished reading it during iter t-1, proven by the iter-t barrier.
// ---------------------------------------------------------------------------
template <int TBM, int TBN, int GX, int GY, bool XMAJOR, int SPLIT, typename CT>
__global__ __launch_bounds__(256 * SPLIT) void gemm_bt_bf16(
    const unsigned short* __restrict__ A, const unsigned short* __restrict__ B,
    CT* __restrict__ C, int aRG, int bRG, int M, int N, int K) {
  constexpr int MF = TBM / 32;
  constexpr int NF = TBN / 32;
  constexpr int NSA = TBM / 16;
  constexpr int NSB = TBN / 16;
  constexpr int LPW = (NSA + NSB) / 4;
  static_assert((NSA + NSB) % 4 == 0, "segments must split evenly over waves");
  constexpr int NWG = GX * GY;
  constexpr int PER = NWG / 8;
  static_assert(NWG % 8 == 0, "grid must split evenly over 8 XCDs");
  __shared__ unsigned short Asm[SPLIT][3][TBM * 32];
  __shared__ unsigned short Bsm[SPLIT][3][TBN * 32];

  const int tid = threadIdx.x;
  const int w = tid >> 6, lane = tid & 63;
  const int khalf = w >> 2;        // 0 for SPLIT=1
  const int wv = w & 3;
  const int kTiles = (K / SPLIT) >> 5;
  const int ktBase = khalf * kTiles;

  const int g = (blockIdx.x & 7) * PER + (blockIdx.x >> 3);
  int bx, by;
  if constexpr (XMAJOR) { by = g / GX; bx = g - by * GX; }
  else                  { bx = g / GY; by = g - bx * GY; }
  const int bm = by * TBM, bn = bx * TBN;

  const int wm = (wv & 1) * (TBM / 2);
  const int wn = (wv >> 1) * (TBN / 2);
  const int gq = lane >> 4, r = lane & 15;

  f32x4 acc[MF][NF];
#pragma unroll
  for (int i = 0; i < MF; ++i)
#pragma unroll
    for (int j = 0; j < NF; ++j) acc[i][j] = (f32x4){0.f, 0.f, 0.f, 0.f};

  auto stage = [&](int t, int buf) {
    const int kt = ktBase + t;
    for (int s = wv; s < NSA + NSB; s += 4) {
      if (s < NSA) {
        const unsigned short* src =
            A + ((size_t)kt * aRG + (bm >> 6) + (s >> 2)) * 2048 + (s & 3) * 512 + lane * 8;
        gload_lds16(src, (void*)(&Asm[khalf][buf][s * 512]));
      } else {
        int s2 = s - NSA;
        const unsigned short* src =
            B + ((size_t)kt * bRG + (bn >> 6) + (s2 >> 2)) * 2048 + (s2 & 3) * 512 + lane * 8;
        gload_lds16(src, (void*)(&Bsm[khalf][buf][s2 * 512]));
      }
    }
  };

  stage(0, 0);
  stage(1, 1);

  int cur = 0;
  for (int t = 0; t < kTiles; ++t) {
    if (t + 1 < kTiles) wait_vm<LPW>();   // tile t landed; t+1 may be in flight
    else                wait_vm<0>();
    __builtin_amdgcn_s_barrier();
    asm volatile("" ::: "memory");        // fence: s_barrier is IntrNoMem

    if (t + 2 < kTiles) stage(t + 2, (t + 2) % 3);

    short8 a[MF], b[NF];
#pragma unroll
    for (int mf = 0; mf < MF; ++mf) {
      int ra = wm + mf * 16 + r;
      a[mf] = *(const short8*)&Asm[khalf][cur][(ra >> 6) * 2048 + gq * 512 + (ra & 63) * 8];
    }
#pragma unroll
    for (int nf = 0; nf < NF; ++nf) {
      int rb = wn + nf * 16 + r;
      b[nf] = *(const short8*)&Bsm[khalf][cur][(rb >> 6) * 2048 + gq * 512 + (rb & 63) * 8];
    }
#pragma unroll
    for (int mf = 0; mf < MF; ++mf)
#pragma unroll
      for (int nf = 0; nf < NF; ++nf)
        acc[mf][nf] = __builtin_amdgcn_mfma_f32_16x16x32_bf16(a[mf], b[nf], acc[mf][nf], 0, 0, 0);

    cur = (cur + 1) % 3;
  }

  if constexpr (SPLIT == 2) {
    // merge K-half partials through LDS (16 KB region in half-0's A buffers)
    __syncthreads();
    float* red = (float*)&Asm[0][0][0];
    if (khalf == 1) {
#pragma unroll
      for (int mf = 0; mf < MF; ++mf)
#pragma unroll
        for (int nf = 0; nf < NF; ++nf)
#pragma unroll
          for (int q = 0; q < 4; ++q)
            red[(size_t)wv * 1024 + ((mf * NF + nf) * 4 + q) * 64 + lane] = acc[mf][nf][q];
    }
    __syncthreads();
    if (khalf == 1) return;
#pragma unroll
    for (int mf = 0; mf < MF; ++mf)
#pragma unroll
      for (int nf = 0; nf < NF; ++nf)
#pragma unroll
        for (int q = 0; q < 4; ++q)
          acc[mf][nf][q] += red[(size_t)wv * 1024 + ((mf * NF + nf) * 4 + q) * 64 + lane];
  }

  // C write: D row = (lane>>4)*4 + q, col = lane&15 (m89-verified layout)
#pragma unroll
  for (int mf = 0; mf < MF; ++mf) {
#pragma unroll
    for (int nf = 0; nf < NF; ++nf) {
      int col = bn + wn + nf * 16 + r;
      if (col < N) {
#pragma unroll
        for (int q = 0; q < 4; ++q) {
          int row = bm + wm + mf * 16 + gq * 4 + q;
          storeC(acc[mf][nf][q], &C[(size_t)row * N + col]);
        }
      }
    }
  }
}

// ---------------------------------------------------------------------------
// Prep: LN(B), LN(C) -> BC (bf16); a=A*DT, DT -> aDT. proj is bf16.
// ---------------------------------------------------------------------------
__device__ __forceinline__ float softplusf(float x) {
  return (x > 20.f) ? x : log1pf(expf(x));
}
__device__ __forceinline__ float wave_sum64(float v) {
#pragma unroll
  for (int o = 32; o > 0; o >>= 1) v += __shfl_xor(v, o);
  return v;
}

__global__ __launch_bounds__(256) void prep_kernel(
    const unsigned short* __restrict__ proj, const float* __restrict__ dt_bias,
    const float* __restrict__ Bg, const float* __restrict__ Bb,
    const float* __restrict__ Cg, const float* __restrict__ Cb,
    unsigned short* __restrict__ BC, float2* __restrict__ aDT) {
  const int r = blockIdx.x * 4 + (threadIdx.x >> 6);
  const int lane = threadIdx.x & 63;
  const unsigned short* p = proj + (size_t)r * D_PROJ;

  float bp = bf2f(p[2 * D_INNER + lane]);
  float cp = bf2f(p[2 * D_INNER + D_STATE + lane]);

  float mb = wave_sum64(bp) * (1.f / 64.f);
  float mc = wave_sum64(cp) * (1.f / 64.f);
  float db = bp - mb, dc = cp - mc;
  float vb = wave_sum64(db * db) * (1.f / 64.f);
  float vc = wave_sum64(dc * dc) * (1.f / 64.f);
  float bn = db * rsqrtf(vb + LN_EPS) * Bg[lane] + Bb[lane];
  float cn = dc * rsqrtf(vc + LN_EPS) * Cg[lane] + Cb[lane];
  BC[(size_t)r * 128 + lane]      = f2bf(bn);
  BC[(size_t)r * 128 + 64 + lane] = f2bf(cn);

  if (lane < NHEADS) {
    float ddt = bf2f(p[2 * D_INNER + 2 * D_STATE + lane]);
    float dA  = bf2f(p[2 * D_INNER + 2 * D_STATE + NHEADS + lane]);
    float DT = softplusf(ddt + dt_bias[lane]);
    float Aa = fminf(-softplusf(dA), -A_FLOOR);
    int b = r >> 10;
    int t = r & 1023;
    aDT[((size_t)(b * NHEADS + lane) << 10) + t] = make_float2(Aa * DT, DT);
  }
}

__device__ __forceinline__ float wave_prefix_incl(float v, int lane) {
#pragma unroll
  for (int o = 1; o < 64; o <<= 1) {
    float w = __shfl_up(v, o);
    if (lane >= o) v += w;
  }
  return v;
}

// ---------------------------------------------------------------------------
// chunk_state (MFMA): T[n][p] = sum_s B[s][n] * (coeff_s * x[s][p])
// ---------------------------------------------------------------------------
__global__ __launch_bounds__(256) void chunk_state_kernel(
    const unsigned short* __restrict__ proj, const unsigned short* __restrict__ BC,
    const float2* __restrict__ aDT, float* __restrict__ Tbuf,
    float* __restrict__ Ebuf) {
  const int blk = blockIdx.x;
  const int c = blk & (NCH - 1), bh = blk >> 4;
  const int b = bh / NHEADS, hh = bh % NHEADS;
  const int tid = threadIdx.x;

  __shared__ unsigned short BT[64 * LSTR];  // [n][s]
  __shared__ unsigned short XT[64 * LSTR];  // [p][s]
  __shared__ float coeff[QC];
  __shared__ float etot[1];

  if (tid < 64) {
    float2 ad = aDT[((size_t)bh << 10) + c * QC + tid];
    float cs = wave_prefix_incl(ad.x, tid);
    float tot = __shfl(cs, 63);
    coeff[tid] = ad.y * __expf(tot - cs);
    if (tid == 63) etot[0] = __expf(tot);
  }
  __syncthreads();

  for (int i = tid; i < 1024; i += 256) {
    int s = i >> 4;
    int q = (i & 15) * 4;
    int r = b * SEQ + c * QC + s;
    ushort4 bv = *(const ushort4*)(BC + (size_t)r * 128 + q);
    ushort4 xv = *(const ushort4*)(proj + (size_t)r * D_PROJ + D_INNER + hh * 64 + q);
    float cf = coeff[s];
    BT[(q + 0) * LSTR + s] = bv.x;
    BT[(q + 1) * LSTR + s] = bv.y;
    BT[(q + 2) * LSTR + s] = bv.z;
    BT[(q + 3) * LSTR + s] = bv.w;
    XT[(q + 0) * LSTR + s] = f2bf(bf2f(xv.x) * cf);
    XT[(q + 1) * LSTR + s] = f2bf(bf2f(xv.y) * cf);
    XT[(q + 2) * LSTR + s] = f2bf(bf2f(xv.z) * cf);
    XT[(q + 3) * LSTR + s] = f2bf(bf2f(xv.w) * cf);
  }
  __syncthreads();

  const int w = tid >> 6, l = tid & 63;
  const int r16 = l & 15, g = l >> 4;
  f32x4 acc[4];
#pragma unroll
  for (int i = 0; i < 4; ++i) acc[i] = (f32x4){0.f, 0.f, 0.f, 0.f};

#pragma unroll
  for (int kk = 0; kk < 2; ++kk) {
    short8 a = *(const short8*)&BT[(w * 16 + r16) * LSTR + kk * 32 + g * 8];
#pragma unroll
    for (int pf = 0; pf < 4; ++pf) {
      short8 bf = *(const short8*)&XT[(pf * 16 + r16) * LSTR + kk * 32 + g * 8];
      acc[pf] = __builtin_amdgcn_mfma_f32_16x16x32_bf16(a, bf, acc[pf], 0, 0, 0);
    }
  }

  float* T = Tbuf + (size_t)blk * 4096;
#pragma unroll
  for (int pf = 0; pf < 4; ++pf)
#pragma unroll
    for (int q = 0; q < 4; ++q)
      T[(size_t)(w * 16 + g * 4 + q) * 64 + pf * 16 + r16] = acc[pf][q];
  if (tid == 0) Ebuf[blk] = etot[0];
}

// ---------------------------------------------------------------------------
// interchunk: S_in[c+1] = E_c * S_in[c] + T_c
// ---------------------------------------------------------------------------
__global__ __launch_bounds__(256) void interchunk_kernel(
    const float* __restrict__ Tbuf, const float* __restrict__ Ebuf,
    float* __restrict__ Sinbuf) {
  const int bh = blockIdx.x >> 2, part = blockIdx.x & 3;
  const int tid = threadIdx.x;
  const size_t eo = (size_t)part * 1024 + tid * 4;
  float4 s = make_float4(0.f, 0.f, 0.f, 0.f);
#pragma unroll
  for (int c = 0; c < NCH; ++c) {
    size_t off = ((size_t)(bh * NCH + c)) * 4096 + eo;
    *(float4*)(Sinbuf + off) = s;
    float E = Ebuf[bh * NCH + c];
    float4 t4 = *(const float4*)(Tbuf + off);
    s.x = fmaf(E, s.x, t4.x);
    s.y = fmaf(E, s.y, t4.y);
    s.z = fmaf(E, s.z, t4.z);
    s.w = fmaf(E, s.w, t4.w);
  }
}

// ---------------------------------------------------------------------------
// chunk_output (MFMA): G=Cc@Bc^T, CS=Cc@SinT, mask G->W, Y=exp*CS+W@X+D*x,
// silu(z) gate -> PACKED bf16 Ypk.
// ---------------------------------------------------------------------------
__global__ __launch_bounds__(256) void chunk_output_kernel(
    const unsigned short* __restrict__ proj, const unsigned short* __restrict__ BC,
    const float2* __restrict__ aDT, const float* __restrict__ Sinbuf,
    const float* __restrict__ Dv, unsigned short* __restrict__ Ybf) {
  const int blk = blockIdx.x;
  const int c = blk & (NCH - 1), bh = blk >> 4;
  const int b = bh / NHEADS, hh = bh % NHEADS;
  const int tid = threadIdx.x;

  __shared__ unsigned short Cc[64 * LSTR];    // [t][n]
  __shared__ unsigned short Bc[64 * LSTR];    // [s][n]
  __shared__ unsigned short SinT[64 * LSTR];  // [p][n]
  __shared__ unsigned short XT[64 * LSTR];    // [p][s]
  __shared__ unsigned short Wl[64 * LSTR];    // [t][s]
  __shared__ float csum[QC];
  __shared__ float DTs[QC];

  if (tid < 64) {
    float2 ad = aDT[((size_t)bh << 10) + c * QC + tid];
    csum[tid] = wave_prefix_incl(ad.x, tid);
    DTs[tid] = ad.y;
  }

  const size_t sin_base = (size_t)blk * 4096;
  for (int i = tid; i < 1024; i += 256) {
    int s = i >> 4;
    int q = (i & 15) * 4;
    int r = b * SEQ + c * QC + s;
    ushort4 bv = *(const ushort4*)(BC + (size_t)r * 128 + q);
    ushort4 cv = *(const ushort4*)(BC + (size_t)r * 128 + 64 + q);
    ushort4 xv = *(const ushort4*)(proj + (size_t)r * D_PROJ + D_INNER + hh * 64 + q);
    float4 sv = *(const float4*)(Sinbuf + sin_base + (size_t)s * 64 + q);
    *(ushort4*)&Cc[s * LSTR + q] = cv;
    *(ushort4*)&Bc[s * LSTR + q] = bv;
    XT[(q + 0) * LSTR + s] = xv.x;
    XT[(q + 1) * LSTR + s] = xv.y;
    XT[(q + 2) * LSTR + s] = xv.z;
    XT[(q + 3) * LSTR + s] = xv.w;
    SinT[(q + 0) * LSTR + s] = f2bf(sv.x);
    SinT[(q + 1) * LSTR + s] = f2bf(sv.y);
    SinT[(q + 2) * LSTR + s] = f2bf(sv.z);
    SinT[(q + 3) * LSTR + s] = f2bf(sv.w);
  }
  __syncthreads();

  const int w = tid >> 6, l = tid & 63;
  const int r16 = l & 15, g = l >> 4;

  f32x4 accg[4], accy[4];
#pragma unroll
  for (int i = 0; i < 4; ++i) {
    accg[i] = (f32x4){0.f, 0.f, 0.f, 0.f};
    accy[i] = (f32x4){0.f, 0.f, 0.f, 0.f};
  }

#pragma unroll
  for (int kk = 0; kk < 2; ++kk) {
    short8 a = *(const short8*)&Cc[(w * 16 + r16) * LSTR + kk * 32 + g * 8];
#pragma unroll
    for (int f = 0; f < 4; ++f) {
      short8 bf = *(const short8*)&Bc[(f * 16 + r16) * LSTR + kk * 32 + g * 8];
      accg[f] = __builtin_amdgcn_mfma_f32_16x16x32_bf16(a, bf, accg[f], 0, 0, 0);
    }
#pragma unroll
    for (int f = 0; f < 4; ++f) {
      short8 bf = *(const short8*)&SinT[(f * 16 + r16) * LSTR + kk * 32 + g * 8];
      accy[f] = __builtin_amdgcn_mfma_f32_16x16x32_bf16(a, bf, accy[f], 0, 0, 0);
    }
  }

  float cst[4], dsc[4];
#pragma unroll
  for (int q = 0; q < 4; ++q) {
    cst[q] = csum[w * 16 + g * 4 + q];
    dsc[q] = __expf(cst[q]);
  }
#pragma unroll
  for (int sf = 0; sf < 4; ++sf) {
    int s = sf * 16 + r16;
    float cs_s = csum[s], dt_s = DTs[s];
#pragma unroll
    for (int q = 0; q < 4; ++q) {
      int t = w * 16 + g * 4 + q;
      float wv = (s <= t) ? accg[sf][q] * __expf(cst[q] - cs_s) * dt_s : 0.f;
      Wl[t * LSTR + s] = f2bf(wv);
    }
  }
#pragma unroll
  for (int f = 0; f < 4; ++f)
#pragma unroll
    for (int q = 0; q < 4; ++q) accy[f][q] *= dsc[q];
  __syncthreads();

#pragma unroll
  for (int kk = 0; kk < 2; ++kk) {
    short8 a = *(const short8*)&Wl[(w * 16 + r16) * LSTR + kk * 32 + g * 8];
#pragma unroll
    for (int f = 0; f < 4; ++f) {
      short8 bf = *(const short8*)&XT[(f * 16 + r16) * LSTR + kk * 32 + g * 8];
      accy[f] = __builtin_amdgcn_mfma_f32_16x16x32_bf16(a, bf, accy[f], 0, 0, 0);
    }
  }

  const float Dh = Dv[hh];
  const int rg = b * 16 + c;
#pragma unroll
  for (int pf = 0; pf < 4; ++pf) {
    int p = pf * 16 + r16;
    int col = hh * 64 + p;
    int kt = col >> 5;
    int cseg = (col >> 3) & 3;
    int jj = p & 7;
    size_t base = ((size_t)(kt * RG_U + rg) * 4 + cseg) * 512 + jj;
#pragma unroll
    for (int q = 0; q < 4; ++q) {
      int t = w * 16 + g * 4 + q;
      int rr = b * SEQ + c * QC + t;
      float x = bf2f(proj[(size_t)rr * D_PROJ + D_INNER + hh * 64 + p]);
      float z = bf2f(proj[(size_t)rr * D_PROJ + hh * 64 + p]);
      float y = accy[pf][q] + Dh * x;
      Ybf[base + (size_t)t * 8] = f2bf(y * (z / (1.f + __expf(-z))));
    }
  }
}

// ---------------------------------------------------------------------------
// Launch (R12 structure — best measured: 78.9 us)
// ---------------------------------------------------------------------------
extern "C" void kernel_launch(void* const* d_in, const int* in_sizes, int n_in,
                              void* d_out, int out_size, void* d_ws, size_t ws_size,
                              hipStream_t stream) {
  const float* u       = (const float*)d_in[0];
  const float* Win     = (const float*)d_in[1];
  const float* Wout    = (const float*)d_in[2];
  const float* dt_bias = (const float*)d_in[3];
  const float* Dv      = (const float*)d_in[4];
  const float* Bg      = (const float*)d_in[5];
  const float* Bb      = (const float*)d_in[6];
  const float* Cg      = (const float*)d_in[7];
  const float* Cb      = (const float*)d_in[8];
  float* out = (float*)d_out;

  float* ws = (float*)d_ws;
  unsigned short* projsh = (unsigned short*)ws;
  float*  after_proj = ws + (size_t)ROWS * D_PROJ / 2;
  unsigned short* BCsh = (unsigned short*)after_proj;
  float*  aDTf    = after_proj + (size_t)ROWS * 128 / 2;
  float2* aDT     = (float2*)aDTf;
  float*  Tbuf    = aDTf + (size_t)2 * BATCH * NHEADS * SEQ;
  float*  Ebuf    = Tbuf + (size_t)BATCH * NHEADS * NCH * 4096;
  float*  Sinbuf  = Ebuf + 1024;
  float*  Woutbff = Sinbuf + (size_t)BATCH * NHEADS * NCH * 4096;

  // packed bf16 buffers aliased onto dead f32 regions (lifetimes verified):
  unsigned short* upk   = (unsigned short*)Sinbuf;   // dead before interchunk
  unsigned short* Winpk = (unsigned short*)Tbuf;     // dead before chunk_state
  unsigned short* Ypk   = (unsigned short*)Tbuf;     // after interchunk read Tbuf
  unsigned short* Wopk  = (unsigned short*)Woutbff;  // standalone

  // cast+pack (one fused launch)
  pack_all_kernel<<<KT_1 * RG_U + KT_1 * RG_WIN + KT_2 * RG_WO, 256, 0, stream>>>(
      u, Win, Wout, upk, Winpk, Wopk);

  // 1) proj = u @ Win.T  -> bf16 proj (128x128, 3-buf single-barrier)
  gemm_bt_bf16<128, 128, 26, 16, false, 1, unsigned short><<<416, 256, 0, stream>>>(
      upk, Winpk, projsh, RG_U, RG_WIN, ROWS, D_PROJ, D_MODEL);

  // 2) LN(B), LN(C) -> bf16 BC; a/DT
  prep_kernel<<<ROWS / 4, 256, 0, stream>>>(projsh, dt_bias, Bg, Bb, Cg, Cb, BCsh, aDT);

  // 3) chunked scan (MFMA chunk kernels)
  chunk_state_kernel<<<BATCH * NHEADS * NCH, 256, 0, stream>>>(projsh, BCsh, aDT, Tbuf, Ebuf);
  interchunk_kernel<<<BATCH * NHEADS * 4, 256, 0, stream>>>(Tbuf, Ebuf, Sinbuf);
  chunk_output_kernel<<<BATCH * NHEADS * NCH, 256, 0, stream>>>(projsh, BCsh, aDT, Sinbuf, Dv, Ypk);

  // 4) out = Y @ Wout.T  (in-block split-K=2, 512 threads, direct write)
  gemm_bt_bf16<64, 64, 12, 32, true, 2, float><<<384, 512, 0, stream>>>(
      Ypk, Wopk, out, RG_U, RG_WO, ROWS, D_MODEL, D_INNER);
}

// Round 15
// 76.590 us; speedup vs baseline: 1.1478x; 1.0221x over previous
//
#include <hip/hip_runtime.h>
#include <cstdint>

#define D_MODEL   768
#define D_STATE   64
#define D_INNER   1536
#define NHEADS    24
#define HEADDIM   64
#define D_PROJ    3248
#define BATCH     2
#define SEQ       1024
#define ROWS      (BATCH*SEQ)   // 2048
#define LN_EPS    1e-5f
#define A_FLOOR   1e-4f
#define QC        64            // chunk length
#define NCH       (SEQ/QC)      // 16
#define LSTR      72            // LDS row stride in shorts (144B = 9*16B)

// packed-operand geometry: [kt][rg][c4][64 rows][8 bf16] (4KB per (kt,rg))
#define RG_U    32
#define RG_WIN  52
#define RG_WO   12
#define KT_1    24
#define KT_2    48

typedef __attribute__((ext_vector_type(8))) short short8;
typedef __attribute__((ext_vector_type(4))) float f32x4;

__device__ __forceinline__ unsigned short f2bf(float f) {
  union { float f; uint32_t u; } v; v.f = f;
  uint32_t r = (v.u + 0x7FFFu + ((v.u >> 16) & 1u)) >> 16;
  return (unsigned short)r;
}
__device__ __forceinline__ float bf2f(unsigned short u) {
  union { uint32_t u; float f; } v; v.u = (uint32_t)u << 16;
  return v.f;
}
__device__ __forceinline__ void storeC(float v, float* p) { *p = v; }
__device__ __forceinline__ void storeC(float v, unsigned short* p) { *p = f2bf(v); }

__device__ __forceinline__ void gload_lds16(const void* g, void* l) {
  __builtin_amdgcn_global_load_lds(
      (const __attribute__((address_space(1))) unsigned int*)g,
      (__attribute__((address_space(3))) unsigned int*)l, 16, 0, 0);
}

template <int N>
__device__ __forceinline__ void wait_vm() {
  static_assert(N == 0 || N == 2 || N == 3 || N == 4 || N == 6 || N == 8,
                "unsupported vmcnt");
  if constexpr (N == 0) asm volatile("s_waitcnt vmcnt(0)" ::: "memory");
  else if constexpr (N == 2) asm volatile("s_waitcnt vmcnt(2)" ::: "memory");
  else if constexpr (N == 3) asm volatile("s_waitcnt vmcnt(3)" ::: "memory");
  else if constexpr (N == 4) asm volatile("s_waitcnt vmcnt(4)" ::: "memory");
  else if constexpr (N == 6) asm volatile("s_waitcnt vmcnt(6)" ::: "memory");
  else if constexpr (N == 8) asm volatile("s_waitcnt vmcnt(8)" ::: "memory");
}

// ---------------------------------------------------------------------------
// Pack f32 row-major -> bf16 [kt][rg][c][64][8].
// ---------------------------------------------------------------------------
__global__ __launch_bounds__(256) void pack_all_kernel(
    const float* __restrict__ u, const float* __restrict__ Win,
    const float* __restrict__ Wout, unsigned short* __restrict__ upk,
    unsigned short* __restrict__ Winpk, unsigned short* __restrict__ Wopk) {
  int b = blockIdx.x;
  const float* src; unsigned short* dst; int K, RG, kt, rg, srcRows;
  if (b < KT_1 * RG_U) {
    src = u; dst = upk; K = 768; RG = RG_U; kt = b / RG_U; rg = b % RG_U; srcRows = ROWS;
  } else if (b < KT_1 * RG_U + KT_1 * RG_WIN) {
    int i = b - KT_1 * RG_U;
    src = Win; dst = Winpk; K = 768; RG = RG_WIN; kt = i / RG_WIN; rg = i % RG_WIN; srcRows = D_PROJ;
  } else {
    int i = b - KT_1 * RG_U - KT_1 * RG_WIN;
    src = Wout; dst = Wopk; K = 1536; RG = RG_WO; kt = i / RG_WO; rg = i % RG_WO; srcRows = D_MODEL;
  }
  const int t = threadIdx.x;
  const int lr = t >> 2, cq = t & 3;
  const int R = rg * 64 + lr;
  float4 v0 = make_float4(0.f, 0.f, 0.f, 0.f), v1 = v0;
  if (R < srcRows) {
    const float* p = src + (size_t)R * K + kt * 32 + cq * 8;
    v0 = *(const float4*)p;
    v1 = *(const float4*)(p + 4);
  }
  ushort4 oa, ob;
  oa.x = f2bf(v0.x); oa.y = f2bf(v0.y); oa.z = f2bf(v0.z); oa.w = f2bf(v0.w);
  ob.x = f2bf(v1.x); ob.y = f2bf(v1.y); ob.z = f2bf(v1.z); ob.w = f2bf(v1.w);
  unsigned short* o = dst + ((size_t)(kt * RG + rg) * 4 + cq) * 512 + lr * 8;
  *(ushort4*)o = oa;
  *(ushort4*)(o + 4) = ob;
}

// ---------------------------------------------------------------------------
// MFMA bf16 GEMM (NT), packed operands. 3-buffer / prefetch-distance-2 /
// ONE barrier per K-iter. XCD panel swizzle. SPLIT=2: in-block split-K with
// 2*256 threads (waves 0-3 = K-half 0, waves 4-7 = K-half 1 on private LDS
// pipelines), f32 partial merge via LDS in epilogue.
// ---------------------------------------------------------------------------
template <int TBM, int TBN, int GX, int GY, bool XMAJOR, int SPLIT, typename CT>
__global__ __launch_bounds__(256 * SPLIT) void gemm_bt_bf16(
    const unsigned short* __restrict__ A, const unsigned short* __restrict__ B,
    CT* __restrict__ C, int aRG, int bRG, int M, int N, int K) {
  constexpr int MF = TBM / 32;
  constexpr int NF = TBN / 32;
  constexpr int NSA = TBM / 16;
  constexpr int NSB = TBN / 16;
  constexpr int LPW = (NSA + NSB) / 4;
  static_assert((NSA + NSB) % 4 == 0, "segments must split evenly over waves");
  constexpr int NWG = GX * GY;
  constexpr int PER = NWG / 8;
  static_assert(NWG % 8 == 0, "grid must split evenly over 8 XCDs");
  __shared__ unsigned short Asm[SPLIT][3][TBM * 32];
  __shared__ unsigned short Bsm[SPLIT][3][TBN * 32];

  const int tid = threadIdx.x;
  const int w = tid >> 6, lane = tid & 63;
  const int khalf = w >> 2;        // 0 for SPLIT=1
  const int wv = w & 3;
  const int kTiles = (K / SPLIT) >> 5;
  const int ktBase = khalf * kTiles;

  const int g = (blockIdx.x & 7) * PER + (blockIdx.x >> 3);
  int bx, by;
  if constexpr (XMAJOR) { by = g / GX; bx = g - by * GX; }
  else                  { bx = g / GY; by = g - bx * GY; }
  const int bm = by * TBM, bn = bx * TBN;

  const int wm = (wv & 1) * (TBM / 2);
  const int wn = (wv >> 1) * (TBN / 2);
  const int gq = lane >> 4, r = lane & 15;

  f32x4 acc[MF][NF];
#pragma unroll
  for (int i = 0; i < MF; ++i)
#pragma unroll
    for (int j = 0; j < NF; ++j) acc[i][j] = (f32x4){0.f, 0.f, 0.f, 0.f};

  auto stage = [&](int t, int buf) {
    const int kt = ktBase + t;
    for (int s = wv; s < NSA + NSB; s += 4) {
      if (s < NSA) {
        const unsigned short* src =
            A + ((size_t)kt * aRG + (bm >> 6) + (s >> 2)) * 2048 + (s & 3) * 512 + lane * 8;
        gload_lds16(src, (void*)(&Asm[khalf][buf][s * 512]));
      } else {
        int s2 = s - NSA;
        const unsigned short* src =
            B + ((size_t)kt * bRG + (bn >> 6) + (s2 >> 2)) * 2048 + (s2 & 3) * 512 + lane * 8;
        gload_lds16(src, (void*)(&Bsm[khalf][buf][s2 * 512]));
      }
    }
  };

  stage(0, 0);
  stage(1, 1);

  int cur = 0;
  for (int t = 0; t < kTiles; ++t) {
    if (t + 1 < kTiles) wait_vm<LPW>();   // tile t landed; t+1 may be in flight
    else                wait_vm<0>();
    __builtin_amdgcn_s_barrier();
    asm volatile("" ::: "memory");        // fence: s_barrier is IntrNoMem

    if (t + 2 < kTiles) stage(t + 2, (t + 2) % 3);

    short8 a[MF], b[NF];
#pragma unroll
    for (int mf = 0; mf < MF; ++mf) {
      int ra = wm + mf * 16 + r;
      a[mf] = *(const short8*)&Asm[khalf][cur][(ra >> 6) * 2048 + gq * 512 + (ra & 63) * 8];
    }
#pragma unroll
    for (int nf = 0; nf < NF; ++nf) {
      int rb = wn + nf * 16 + r;
      b[nf] = *(const short8*)&Bsm[khalf][cur][(rb >> 6) * 2048 + gq * 512 + (rb & 63) * 8];
    }
#pragma unroll
    for (int mf = 0; mf < MF; ++mf)
#pragma unroll
      for (int nf = 0; nf < NF; ++nf)
        acc[mf][nf] = __builtin_amdgcn_mfma_f32_16x16x32_bf16(a[mf], b[nf], acc[mf][nf], 0, 0, 0);

    cur = (cur + 1) % 3;
  }

  if constexpr (SPLIT == 2) {
    // merge K-half partials through LDS (16 KB region in half-0's A buffers)
    __syncthreads();
    float* red = (float*)&Asm[0][0][0];
    if (khalf == 1) {
#pragma unroll
      for (int mf = 0; mf < MF; ++mf)
#pragma unroll
        for (int nf = 0; nf < NF; ++nf)
#pragma unroll
          for (int q = 0; q < 4; ++q)
            red[(size_t)wv * 1024 + ((mf * NF + nf) * 4 + q) * 64 + lane] = acc[mf][nf][q];
    }
    __syncthreads();
    if (khalf == 1) return;
#pragma unroll
    for (int mf = 0; mf < MF; ++mf)
#pragma unroll
      for (int nf = 0; nf < NF; ++nf)
#pragma unroll
        for (int q = 0; q < 4; ++q)
          acc[mf][nf][q] += red[(size_t)wv * 1024 + ((mf * NF + nf) * 4 + q) * 64 + lane];
  }

  // C write: D row = (lane>>4)*4 + q, col = lane&15 (m89-verified layout)
#pragma unroll
  for (int mf = 0; mf < MF; ++mf) {
#pragma unroll
    for (int nf = 0; nf < NF; ++nf) {
      int col = bn + wn + nf * 16 + r;
      if (col < N) {
#pragma unroll
        for (int q = 0; q < 4; ++q) {
          int row = bm + wm + mf * 16 + gq * 4 + q;
          storeC(acc[mf][nf][q], &C[(size_t)row * N + col]);
        }
      }
    }
  }
}

// ---------------------------------------------------------------------------
// Prep: LN(B), LN(C) -> BC (bf16); a=A*DT, DT -> aDT. proj is bf16.
// ---------------------------------------------------------------------------
__device__ __forceinline__ float softplusf(float x) {
  return (x > 20.f) ? x : log1pf(expf(x));
}
__device__ __forceinline__ float wave_sum64(float v) {
#pragma unroll
  for (int o = 32; o > 0; o >>= 1) v += __shfl_xor(v, o);
  return v;
}

__global__ __launch_bounds__(256) void prep_kernel(
    const unsigned short* __restrict__ proj, const float* __restrict__ dt_bias,
    const float* __restrict__ Bg, const float* __restrict__ Bb,
    const float* __restrict__ Cg, const float* __restrict__ Cb,
    unsigned short* __restrict__ BC, float2* __restrict__ aDT) {
  const int r = blockIdx.x * 4 + (threadIdx.x >> 6);
  const int lane = threadIdx.x & 63;
  const unsigned short* p = proj + (size_t)r * D_PROJ;

  float bp = bf2f(p[2 * D_INNER + lane]);
  float cp = bf2f(p[2 * D_INNER + D_STATE + lane]);

  float mb = wave_sum64(bp) * (1.f / 64.f);
  float mc = wave_sum64(cp) * (1.f / 64.f);
  float db = bp - mb, dc = cp - mc;
  float vb = wave_sum64(db * db) * (1.f / 64.f);
  float vc = wave_sum64(dc * dc) * (1.f / 64.f);
  float bn = db * rsqrtf(vb + LN_EPS) * Bg[lane] + Bb[lane];
  float cn = dc * rsqrtf(vc + LN_EPS) * Cg[lane] + Cb[lane];
  BC[(size_t)r * 128 + lane]      = f2bf(bn);
  BC[(size_t)r * 128 + 64 + lane] = f2bf(cn);

  if (lane < NHEADS) {
    float ddt = bf2f(p[2 * D_INNER + 2 * D_STATE + lane]);
    float dA  = bf2f(p[2 * D_INNER + 2 * D_STATE + NHEADS + lane]);
    float DT = softplusf(ddt + dt_bias[lane]);
    float Aa = fminf(-softplusf(dA), -A_FLOOR);
    int b = r >> 10;
    int t = r & 1023;
    aDT[((size_t)(b * NHEADS + lane) << 10) + t] = make_float2(Aa * DT, DT);
  }
}

__device__ __forceinline__ float wave_prefix_incl(float v, int lane) {
#pragma unroll
  for (int o = 1; o < 64; o <<= 1) {
    float w = __shfl_up(v, o);
    if (lane >= o) v += w;
  }
  return v;
}

// ---------------------------------------------------------------------------
// chunk_state (MFMA): T[n][p] = sum_s B[s][n] * (coeff_s * x[s][p])
// ---------------------------------------------------------------------------
__global__ __launch_bounds__(256) void chunk_state_kernel(
    const unsigned short* __restrict__ proj, const unsigned short* __restrict__ BC,
    const float2* __restrict__ aDT, float* __restrict__ Tbuf,
    float* __restrict__ Ebuf) {
  const int blk = blockIdx.x;
  const int c = blk & (NCH - 1), bh = blk >> 4;
  const int b = bh / NHEADS, hh = bh % NHEADS;
  const int tid = threadIdx.x;

  __shared__ unsigned short BT[64 * LSTR];  // [n][s]
  __shared__ unsigned short XT[64 * LSTR];  // [p][s]
  __shared__ float coeff[QC];
  __shared__ float etot[1];

  if (tid < 64) {
    float2 ad = aDT[((size_t)bh << 10) + c * QC + tid];
    float cs = wave_prefix_incl(ad.x, tid);
    float tot = __shfl(cs, 63);
    coeff[tid] = ad.y * __expf(tot - cs);
    if (tid == 63) etot[0] = __expf(tot);
  }
  __syncthreads();

  for (int i = tid; i < 1024; i += 256) {
    int s = i >> 4;
    int q = (i & 15) * 4;
    int r = b * SEQ + c * QC + s;
    ushort4 bv = *(const ushort4*)(BC + (size_t)r * 128 + q);
    ushort4 xv = *(const ushort4*)(proj + (size_t)r * D_PROJ + D_INNER + hh * 64 + q);
    float cf = coeff[s];
    BT[(q + 0) * LSTR + s] = bv.x;
    BT[(q + 1) * LSTR + s] = bv.y;
    BT[(q + 2) * LSTR + s] = bv.z;
    BT[(q + 3) * LSTR + s] = bv.w;
    XT[(q + 0) * LSTR + s] = f2bf(bf2f(xv.x) * cf);
    XT[(q + 1) * LSTR + s] = f2bf(bf2f(xv.y) * cf);
    XT[(q + 2) * LSTR + s] = f2bf(bf2f(xv.z) * cf);
    XT[(q + 3) * LSTR + s] = f2bf(bf2f(xv.w) * cf);
  }
  __syncthreads();

  const int w = tid >> 6, l = tid & 63;
  const int r16 = l & 15, g = l >> 4;
  f32x4 acc[4];
#pragma unroll
  for (int i = 0; i < 4; ++i) acc[i] = (f32x4){0.f, 0.f, 0.f, 0.f};

#pragma unroll
  for (int kk = 0; kk < 2; ++kk) {
    short8 a = *(const short8*)&BT[(w * 16 + r16) * LSTR + kk * 32 + g * 8];
#pragma unroll
    for (int pf = 0; pf < 4; ++pf) {
      short8 bf = *(const short8*)&XT[(pf * 16 + r16) * LSTR + kk * 32 + g * 8];
      acc[pf] = __builtin_amdgcn_mfma_f32_16x16x32_bf16(a, bf, acc[pf], 0, 0, 0);
    }
  }

  float* T = Tbuf + (size_t)blk * 4096;
#pragma unroll
  for (int pf = 0; pf < 4; ++pf)
#pragma unroll
    for (int q = 0; q < 4; ++q)
      T[(size_t)(w * 16 + g * 4 + q) * 64 + pf * 16 + r16] = acc[pf][q];
  if (tid == 0) Ebuf[blk] = etot[0];
}

// ---------------------------------------------------------------------------
// interchunk: S_in[c+1] = E_c * S_in[c] + T_c
// ---------------------------------------------------------------------------
__global__ __launch_bounds__(256) void interchunk_kernel(
    const float* __restrict__ Tbuf, const float* __restrict__ Ebuf,
    float* __restrict__ Sinbuf) {
  const int bh = blockIdx.x >> 2, part = blockIdx.x & 3;
  const int tid = threadIdx.x;
  const size_t eo = (size_t)part * 1024 + tid * 4;
  float4 s = make_float4(0.f, 0.f, 0.f, 0.f);
#pragma unroll
  for (int c = 0; c < NCH; ++c) {
    size_t off = ((size_t)(bh * NCH + c)) * 4096 + eo;
    *(float4*)(Sinbuf + off) = s;
    float E = Ebuf[bh * NCH + c];
    float4 t4 = *(const float4*)(Tbuf + off);
    s.x = fmaf(E, s.x, t4.x);
    s.y = fmaf(E, s.y, t4.y);
    s.z = fmaf(E, s.z, t4.z);
    s.w = fmaf(E, s.w, t4.w);
  }
}

// ---------------------------------------------------------------------------
// chunk_output (MFMA): G=Cc@Bc^T, CS=Cc@SinT, mask G->W, Y=exp*CS+W@X+D*x,
// silu(z) gate -> PACKED bf16 Ypk. x re-read from XT (LDS) in epilogue.
// ---------------------------------------------------------------------------
__global__ __launch_bounds__(256) void chunk_output_kernel(
    const unsigned short* __restrict__ proj, const unsigned short* __restrict__ BC,
    const float2* __restrict__ aDT, const float* __restrict__ Sinbuf,
    const float* __restrict__ Dv, unsigned short* __restrict__ Ybf) {
  const int blk = blockIdx.x;
  const int c = blk & (NCH - 1), bh = blk >> 4;
  const int b = bh / NHEADS, hh = bh % NHEADS;
  const int tid = threadIdx.x;

  __shared__ unsigned short Cc[64 * LSTR];    // [t][n]
  __shared__ unsigned short Bc[64 * LSTR];    // [s][n]
  __shared__ unsigned short SinT[64 * LSTR];  // [p][n]
  __shared__ unsigned short XT[64 * LSTR];    // [p][s]
  __shared__ unsigned short Wl[64 * LSTR];    // [t][s]
  __shared__ float csum[QC];
  __shared__ float DTs[QC];

  if (tid < 64) {
    float2 ad = aDT[((size_t)bh << 10) + c * QC + tid];
    csum[tid] = wave_prefix_incl(ad.x, tid);
    DTs[tid] = ad.y;
  }

  const size_t sin_base = (size_t)blk * 4096;
  for (int i = tid; i < 1024; i += 256) {
    int s = i >> 4;
    int q = (i & 15) * 4;
    int r = b * SEQ + c * QC + s;
    ushort4 bv = *(const ushort4*)(BC + (size_t)r * 128 + q);
    ushort4 cv = *(const ushort4*)(BC + (size_t)r * 128 + 64 + q);
    ushort4 xv = *(const ushort4*)(proj + (size_t)r * D_PROJ + D_INNER + hh * 64 + q);
    float4 sv = *(const float4*)(Sinbuf + sin_base + (size_t)s * 64 + q);
    *(ushort4*)&Cc[s * LSTR + q] = cv;
    *(ushort4*)&Bc[s * LSTR + q] = bv;
    XT[(q + 0) * LSTR + s] = xv.x;
    XT[(q + 1) * LSTR + s] = xv.y;
    XT[(q + 2) * LSTR + s] = xv.z;
    XT[(q + 3) * LSTR + s] = xv.w;
    SinT[(q + 0) * LSTR + s] = f2bf(sv.x);
    SinT[(q + 1) * LSTR + s] = f2bf(sv.y);
    SinT[(q + 2) * LSTR + s] = f2bf(sv.z);
    SinT[(q + 3) * LSTR + s] = f2bf(sv.w);
  }
  __syncthreads();

  const int w = tid >> 6, l = tid & 63;
  const int r16 = l & 15, g = l >> 4;

  f32x4 accg[4], accy[4];
#pragma unroll
  for (int i = 0; i < 4; ++i) {
    accg[i] = (f32x4){0.f, 0.f, 0.f, 0.f};
    accy[i] = (f32x4){0.f, 0.f, 0.f, 0.f};
  }

#pragma unroll
  for (int kk = 0; kk < 2; ++kk) {
    short8 a = *(const short8*)&Cc[(w * 16 + r16) * LSTR + kk * 32 + g * 8];
#pragma unroll
    for (int f = 0; f < 4; ++f) {
      short8 bf = *(const short8*)&Bc[(f * 16 + r16) * LSTR + kk * 32 + g * 8];
      accg[f] = __builtin_amdgcn_mfma_f32_16x16x32_bf16(a, bf, accg[f], 0, 0, 0);
    }
#pragma unroll
    for (int f = 0; f < 4; ++f) {
      short8 bf = *(const short8*)&SinT[(f * 16 + r16) * LSTR + kk * 32 + g * 8];
      accy[f] = __builtin_amdgcn_mfma_f32_16x16x32_bf16(a, bf, accy[f], 0, 0, 0);
    }
  }

  float cst[4], dsc[4];
#pragma unroll
  for (int q = 0; q < 4; ++q) {
    cst[q] = csum[w * 16 + g * 4 + q];
    dsc[q] = __expf(cst[q]);
  }
#pragma unroll
  for (int sf = 0; sf < 4; ++sf) {
    int s = sf * 16 + r16;
    float cs_s = csum[s], dt_s = DTs[s];
#pragma unroll
    for (int q = 0; q < 4; ++q) {
      int t = w * 16 + g * 4 + q;
      float wv = (s <= t) ? accg[sf][q] * __expf(cst[q] - cs_s) * dt_s : 0.f;
      Wl[t * LSTR + s] = f2bf(wv);
    }
  }
#pragma unroll
  for (int f = 0; f < 4; ++f)
#pragma unroll
    for (int q = 0; q < 4; ++q) accy[f][q] *= dsc[q];
  __syncthreads();

#pragma unroll
  for (int kk = 0; kk < 2; ++kk) {
    short8 a = *(const short8*)&Wl[(w * 16 + r16) * LSTR + kk * 32 + g * 8];
#pragma unroll
    for (int f = 0; f < 4; ++f) {
      short8 bf = *(const short8*)&XT[(f * 16 + r16) * LSTR + kk * 32 + g * 8];
      accy[f] = __builtin_amdgcn_mfma_f32_16x16x32_bf16(a, bf, accy[f], 0, 0, 0);
    }
  }

  const float Dh = Dv[hh];
  const int rg = b * 16 + c;
#pragma unroll
  for (int pf = 0; pf < 4; ++pf) {
    int p = pf * 16 + r16;
    int col = hh * 64 + p;
    int kt = col >> 5;
    int cseg = (col >> 3) & 3;
    int jj = p & 7;
    size_t base = ((size_t)(kt * RG_U + rg) * 4 + cseg) * 512 + jj;
#pragma unroll
    for (int q = 0; q < 4; ++q) {
      int t = w * 16 + g * 4 + q;
      int rr = b * SEQ + c * QC + t;
      float x = bf2f(XT[p * LSTR + t]);   // x from LDS (already staged)
      float z = bf2f(proj[(size_t)rr * D_PROJ + hh * 64 + p]);
      float y = accy[pf][q] + Dh * x;
      Ybf[base + (size_t)t * 8] = f2bf(y * (z / (1.f + __expf(-z))));
    }
  }
}

// ---------------------------------------------------------------------------
// Launch
// ---------------------------------------------------------------------------
extern "C" void kernel_launch(void* const* d_in, const int* in_sizes, int n_in,
                              void* d_out, int out_size, void* d_ws, size_t ws_size,
                              hipStream_t stream) {
  const float* u       = (const float*)d_in[0];
  const float* Win     = (const float*)d_in[1];
  const float* Wout    = (const float*)d_in[2];
  const float* dt_bias = (const float*)d_in[3];
  const float* Dv      = (const float*)d_in[4];
  const float* Bg      = (const float*)d_in[5];
  const float* Bb      = (const float*)d_in[6];
  const float* Cg      = (const float*)d_in[7];
  const float* Cb      = (const float*)d_in[8];
  float* out = (float*)d_out;

  float* ws = (float*)d_ws;
  unsigned short* projsh = (unsigned short*)ws;
  float*  after_proj = ws + (size_t)ROWS * D_PROJ / 2;
  unsigned short* BCsh = (unsigned short*)after_proj;
  float*  aDTf    = after_proj + (size_t)ROWS * 128 / 2;
  float2* aDT     = (float2*)aDTf;
  float*  Tbuf    = aDTf + (size_t)2 * BATCH * NHEADS * SEQ;
  float*  Ebuf    = Tbuf + (size_t)BATCH * NHEADS * NCH * 4096;
  float*  Sinbuf  = Ebuf + 1024;
  float*  Woutbff = Sinbuf + (size_t)BATCH * NHEADS * NCH * 4096;

  // packed bf16 buffers aliased onto dead f32 regions (lifetimes verified):
  unsigned short* upk   = (unsigned short*)Sinbuf;   // dead before interchunk
  unsigned short* Winpk = (unsigned short*)Tbuf;     // dead before chunk_state
  unsigned short* Ypk   = (unsigned short*)Tbuf;     // after interchunk read Tbuf
  unsigned short* Wopk  = (unsigned short*)Woutbff;  // standalone

  // cast+pack (one fused launch)
  pack_all_kernel<<<KT_1 * RG_U + KT_1 * RG_WIN + KT_2 * RG_WO, 256, 0, stream>>>(
      u, Win, Wout, upk, Winpk, Wopk);

  // 1) proj = u @ Win.T  -> bf16 proj (A/B: 64x128 tiles, 832 blocks, 3.25/CU)
  gemm_bt_bf16<64, 128, 26, 32, false, 1, unsigned short><<<832, 256, 0, stream>>>(
      upk, Winpk, projsh, RG_U, RG_WIN, ROWS, D_PROJ, D_MODEL);

  // 2) LN(B), LN(C) -> bf16 BC; a/DT
  prep_kernel<<<ROWS / 4, 256, 0, stream>>>(projsh, dt_bias, Bg, Bb, Cg, Cb, BCsh, aDT);

  // 3) chunked scan (MFMA chunk kernels)
  chunk_state_kernel<<<BATCH * NHEADS * NCH, 256, 0, stream>>>(projsh, BCsh, aDT, Tbuf, Ebuf);
  interchunk_kernel<<<BATCH * NHEADS * 4, 256, 0, stream>>>(Tbuf, Ebuf, Sinbuf);
  chunk_output_kernel<<<BATCH * NHEADS * NCH, 256, 0, stream>>>(projsh, BCsh, aDT, Sinbuf, Dv, Ypk);

  // 4) out = Y @ Wout.T  (in-block split-K=2, 512 threads, direct write)
  gemm_bt_bf16<64, 64, 12, 32, true, 2, float><<<384, 512, 0, stream>>>(
      Ypk, Wopk, out, RG_U, RG_WO, ROWS, D_MODEL, D_INNER);
}